// Round 5
// baseline (22177.290 us; speedup 1.0000x reference)
//
#include <hip/hip_runtime.h>
#include <math.h>

#define BB 64
#define TT 512
#define FF 512
#define DIN 1024
#define HH 1024
#define G4 4096
#define DOUT 128

typedef _Float16 f16;
typedef _Float16 f16x8 __attribute__((ext_vector_type(8)));
typedef float f32x4 __attribute__((ext_vector_type(4)));

// A-fragment-linear layout for a [64 x 1024] fp16 activation matrix:
//   element (m, k) -> ((k>>5)*4 + (m>>4))*512 + ((((k>>3)&3)<<4) | (m&15))*8 + (k&7)
__device__ __forceinline__ size_t afrag_off(int m, int k) {
    return (size_t)(((k >> 5) * 4 + (m >> 4)) * 512 + (((((k >> 3) & 3) << 4) | (m & 15)) * 8) + (k & 7));
}

// ---------------------------------------------------------------------------
// Pack cat(W,U) [2048 x 4096] fp32 -> fp16 B-fragment-linear, z-cols reordered
// as col' = j*4 + g. Per (cg, kstep) a contiguous 1KB fragment tile.
// ---------------------------------------------------------------------------
__global__ __launch_bounds__(64) void k_pack(
    const float* __restrict__ W, const float* __restrict__ U, f16* __restrict__ out)
{
    const int kstep = blockIdx.x, cg = blockIdx.y, l = threadIdx.x;
    const int n = l & 15, q = l >> 4;
    const int stdcol = (n & 3) * HH + cg * 4 + (n >> 2);
    f16x8 v;
#pragma unroll
    for (int e = 0; e < 8; ++e) {
        int k = kstep * 32 + q * 8 + e;
        float s = (k < DIN) ? W[(size_t)k * G4 + stdcol] : U[(size_t)(k - DIN) * G4 + stdcol];
        v[e] = (f16)s;
    }
    *(f16x8*)(out + ((size_t)(cg * 64 + kstep) * 64 + l) * 8) = v;
}

// ---------------------------------------------------------------------------
// Kernel 1: XinF[t] = tanh(x[b][t][:] @ Wi + bi), written fp16 A-frag layout.
// ---------------------------------------------------------------------------
__global__ __launch_bounds__(256) void k_dense_in(
    const float* __restrict__ x, const float* __restrict__ Wi,
    const float* __restrict__ bi, f16* __restrict__ XinF)
{
    __shared__ float xs[16][FF];   // 32 KB
    const int jb  = blockIdx.x;
    const int rb  = blockIdx.y;
    const int tid = threadIdx.x;

    const float4* xsrc = (const float4*)(x + (size_t)rb * 16 * FF);
    float4* xdst = (float4*)(&xs[0][0]);
#pragma unroll
    for (int i = 0; i < 8; ++i) xdst[tid + i * 256] = xsrc[tid + i * 256];
    __syncthreads();

    const int j = jb * 256 + tid;
    float acc[16];
#pragma unroll
    for (int r = 0; r < 16; ++r) acc[r] = 0.f;

    for (int k = 0; k < FF; ++k) {
        float w = Wi[(size_t)k * DIN + j];
#pragma unroll
        for (int r = 0; r < 16; ++r) acc[r] += xs[r][k] * w;
    }
    const float bbv = bi[j];
#pragma unroll
    for (int r = 0; r < 16; ++r) {
        int g = rb * 16 + r;
        int b = g >> 9;
        int t = g & 511;
        XinF[(size_t)t * (BB * DIN) + afrag_off(b, j)] = (f16)tanhf(acc[r] + bbv);
    }
}

// ---------------------------------------------------------------------------
// Custom agent-scope grid barrier: single counter + generation, tid0 protocol.
// Agent scope keeps traffic at L2/L3 (no HBM round-trip like cg::sync).
// ---------------------------------------------------------------------------
__device__ __forceinline__ void gbar(unsigned* cnt, unsigned* gen) {
    __syncthreads();
    if (threadIdx.x == 0) {
        __threadfence();   // release: flush this XCD's L2 (h writes) device-wide
        unsigned g = __hip_atomic_load(gen, __ATOMIC_RELAXED, __HIP_MEMORY_SCOPE_AGENT);
        unsigned a = __hip_atomic_fetch_add(cnt, 1u, __ATOMIC_RELAXED, __HIP_MEMORY_SCOPE_AGENT);
        if (a == 255u) {
            __hip_atomic_store(cnt, 0u, __ATOMIC_RELAXED, __HIP_MEMORY_SCOPE_AGENT);
            __hip_atomic_fetch_add(gen, 1u, __ATOMIC_RELAXED, __HIP_MEMORY_SCOPE_AGENT);
        } else {
            while (__hip_atomic_load(gen, __ATOMIC_RELAXED, __HIP_MEMORY_SCOPE_AGENT) == g)
                __builtin_amdgcn_s_sleep(2);
        }
    }
    __syncthreads();
    __threadfence();       // acquire: invalidate L1/L2 before reading others' h
}

// ---------------------------------------------------------------------------
// Persistent kernel, 256 blocks x 512 threads (1 block/CU), custom barrier.
// Block: lay = bid&1, cgb = bid>>1 (8 hidden units = 2 N-tiles).
// Weights: block's 128 KB B-slice staged in LDS ONCE, ds_read_b128 per phase.
// Waves (8) = kq(4-way K-split) x mh(2 M-halves); each wave: 16 ksteps x
// 2 M x 2 N = 64 MFMAs, A deduped across waves. c lives in registers.
// Epilogue: 2 rounds (per N-tile), 16.6 KB padded reduce buffer.
// ---------------------------------------------------------------------------
__global__ __launch_bounds__(512, 2) void k_persist(
    const f16* __restrict__ XinF,
    f16* __restrict__ h0p0, f16* __restrict__ h0p1,
    f16* __restrict__ h1p0, f16* __restrict__ h1p1,
    const f16* __restrict__ pW0, const f16* __restrict__ pW1,
    const float* __restrict__ b0, const float* __restrict__ b1,
    unsigned* __restrict__ bar)
{
    extern __shared__ char smem[];
    f16*   bsh = (f16*)smem;                    // 131072 B weight fragments
    float* red = (float*)(smem + 131072);       // 16 tiles x 260 floats = 16640 B

    const int lay = blockIdx.x & 1;
    const int cgb = blockIdx.x >> 1;
    const int tid = threadIdx.x;
    const int ws = tid >> 6, lane = tid & 63;
    const int kq = ws >> 1, mh = ws & 1;

    // ---- stage this block's weight slice into LDS (once) ----
    {
        const f16x8* s8 = (const f16x8*)((lay ? pW1 : pW0) + (size_t)(cgb * 2) * 64 * 512);
        f16x8* d8 = (f16x8*)bsh;
#pragma unroll
        for (int it = 0; it < 16; ++it) d8[tid + it * 512] = s8[tid + it * 512];
    }

    // ---- epilogue-role constants (threads 0..255 handle (row, jl) x 2 rounds) ----
    const float* bias = lay ? b1 : b0;
    const int erow = tid & 63, ejl = (tid >> 6) & 3;
    const int emt = erow >> 4, esub = erow & 15;
    const int eslq = (esub >> 2) << 4, ereg = esub & 3;
    float bz[2][4];
    float creg[2] = {0.f, 0.f};
    if (tid < 256) {
#pragma unroll
        for (int n = 0; n < 2; ++n) {
            const int jg = (cgb * 2 + n) * 4 + ejl;
#pragma unroll
            for (int g = 0; g < 4; ++g) bz[n][g] = bias[g * HH + jg];
        }
    }

    unsigned* cnt = bar;
    unsigned* gen = bar + 32;
    const size_t ABUF = (size_t)BB * DIN;
    __syncthreads();

    for (int p = 0; p <= TT; ++p) {
        const bool active = lay ? (p > 0) : (p < TT);
        if (active) {
            const int wp = p & 1, rp = wp ^ 1;
            const f16* h0r = rp ? h0p1 : h0p0;
            const f16* A1 = lay ? h0r : (XinF + (size_t)p * ABUF);
            const f16* A2 = lay ? (rp ? h1p1 : h1p0) : h0r;
            f16* hw = lay ? (wp ? h1p1 : h1p0) : (wp ? h0p1 : h0p0);

            const f16* Ap = ((kq < 2) ? A1 : A2)
                          + (size_t)(((kq & 1) * 64 + mh * 2) * 512) + (size_t)lane * 8;
            const f16* bq = bsh + (size_t)(kq * 16 * 64 + lane) * 8;

            f32x4 acc00 = {0.f,0.f,0.f,0.f}, acc01 = {0.f,0.f,0.f,0.f};
            f32x4 acc10 = {0.f,0.f,0.f,0.f}, acc11 = {0.f,0.f,0.f,0.f};
#pragma unroll
            for (int ii = 0; ii < 16; ++ii) {
                f16x8 a0  = *(const f16x8*)(Ap + (size_t)(ii * 4) * 512);
                f16x8 a1  = *(const f16x8*)(Ap + (size_t)(ii * 4 + 1) * 512);
                f16x8 bb0 = *(const f16x8*)(bq + (size_t)ii * 512);
                f16x8 bb1 = *(const f16x8*)(bq + 32768 + (size_t)ii * 512);
                acc00 = __builtin_amdgcn_mfma_f32_16x16x32_f16(a0, bb0, acc00, 0, 0, 0);
                acc01 = __builtin_amdgcn_mfma_f32_16x16x32_f16(a0, bb1, acc01, 0, 0, 0);
                acc10 = __builtin_amdgcn_mfma_f32_16x16x32_f16(a1, bb0, acc10, 0, 0, 0);
                acc11 = __builtin_amdgcn_mfma_f32_16x16x32_f16(a1, bb1, acc11, 0, 0, 0);
            }

            // ---- two epilogue rounds (N-tile n = 0, 1) ----
#pragma unroll
            for (int n = 0; n < 2; ++n) {
                f32x4 t0 = n ? acc01 : acc00;
                f32x4 t1 = n ? acc11 : acc10;
                *(f32x4*)(red + (size_t)(kq * 4 + mh * 2)     * 260 + lane * 4) = t0;
                *(f32x4*)(red + (size_t)(kq * 4 + mh * 2 + 1) * 260 + lane * 4) = t1;
                __syncthreads();
                if (tid < 256) {
                    float z[4];
#pragma unroll
                    for (int g = 0; g < 4; ++g) {
                        const int sl = eslq | (ejl * 4 + g);
                        float s = 0.f;
#pragma unroll
                        for (int k2 = 0; k2 < 4; ++k2)
                            s += red[(size_t)(k2 * 4 + emt) * 260 + sl * 4 + ereg];
                        z[g] = s + bz[n][g];
                    }
                    const float ig = 1.f / (1.f + expf(-z[0]));
                    const float fg = 1.f / (1.f + expf(-z[1]));
                    const float cc = tanhf(z[2]);
                    const float og = 1.f / (1.f + expf(-z[3]));
                    const float cn = fg * creg[n] + ig * cc;
                    creg[n] = cn;
                    const int jg = (cgb * 2 + n) * 4 + ejl;
                    hw[afrag_off(erow, jg)] = (f16)(og * tanhf(cn));
                }
                __syncthreads();
            }
        }
        gbar(cnt, gen);
    }
}

// ---------------------------------------------------------------------------
// Kernel 3: out[b][o] = tanh(h1[b,:] @ Wo[:,o] + bo[o]); h1 in fp16 A-frag.
// ---------------------------------------------------------------------------
__global__ __launch_bounds__(128) void k_out(
    const f16* __restrict__ h1f, const float* __restrict__ Wo,
    const float* __restrict__ bo, float* __restrict__ out)
{
    __shared__ float hs[HH];
    const int b = blockIdx.x;
    for (int i = threadIdx.x; i < HH; i += 128) hs[i] = (float)h1f[afrag_off(b, i)];
    __syncthreads();
    const int o = threadIdx.x;
    float acc = 0.f;
    for (int k = 0; k < HH; ++k) acc += hs[k] * Wo[k * DOUT + o];
    out[b * DOUT + o] = tanhf(acc + bo[o]);
}

// ---------------------------------------------------------------------------
extern "C" void kernel_launch(void* const* d_in, const int* in_sizes, int n_in,
                              void* d_out, int out_size, void* d_ws, size_t ws_size,
                              hipStream_t stream)
{
    const float* x  = (const float*)d_in[0];
    const float* Wi = (const float*)d_in[1];
    const float* bi = (const float*)d_in[2];
    const float* W0 = (const float*)d_in[3];
    const float* U0 = (const float*)d_in[4];
    const float* b0 = (const float*)d_in[5];
    const float* W1 = (const float*)d_in[6];
    const float* U1 = (const float*)d_in[7];
    const float* b1 = (const float*)d_in[8];
    const float* Wo = (const float*)d_in[9];
    const float* bo = (const float*)d_in[10];
    float* out = (float*)d_out;

    f16* ws16 = (f16*)d_ws;
    const size_t ABUF = (size_t)BB * DIN;
    f16* XinF = ws16;
    f16* pW0  = XinF + (size_t)TT * ABUF;
    f16* pW1  = pW0 + (size_t)2048 * G4;
    f16* h0a  = pW1 + (size_t)2048 * G4;
    f16* h0b  = h0a + ABUF;
    f16* h1a  = h0b + ABUF;
    f16* h1b  = h1a + ABUF;
    unsigned* bar = (unsigned*)(h1b + ABUF);   // cnt at [0], gen at [32]

    // zero h (both parities) + barrier words — contiguous region
    hipMemsetAsync(h0a, 0, 4 * ABUF * sizeof(f16) + 256, stream);

    k_pack<<<dim3(64, 256), 64, 0, stream>>>(W0, U0, pW0);
    k_pack<<<dim3(64, 256), 64, 0, stream>>>(W1, U1, pW1);
    k_dense_in<<<dim3(DIN / 256, (BB * TT) / 16), 256, 0, stream>>>(x, Wi, bi, XinF);

    {
        const int smem_bytes = 131072 + 16640;   // 147712 B
        hipFuncSetAttribute((const void*)k_persist,
                            hipFuncAttributeMaxDynamicSharedMemorySize, smem_bytes);
        const f16* XinF_c = XinF;
        const f16* pW0_c = pW0;
        const f16* pW1_c = pW1;
        f16 *h0a_v = h0a, *h0b_v = h0b, *h1a_v = h1a, *h1b_v = h1b;
        const float *b0_v = b0, *b1_v = b1;
        unsigned* bar_v = bar;
        void* kargs[] = {
            (void*)&XinF_c,
            (void*)&h0a_v, (void*)&h0b_v, (void*)&h1a_v, (void*)&h1b_v,
            (void*)&pW0_c, (void*)&pW1_c,
            (void*)&b0_v, (void*)&b1_v,
            (void*)&bar_v
        };
        hipLaunchCooperativeKernel((void*)k_persist, dim3(256), dim3(512),
                                   kargs, smem_bytes, stream);
    }

    // phase TT writes parity 0 -> h1a holds h1[T-1]
    k_out<<<BB, 128, 0, stream>>>(h1a, Wo, bo, out);
}

// Round 6
// 14662.564 us; speedup vs baseline: 1.5125x; 1.5125x over previous
//
#include <hip/hip_runtime.h>
#include <math.h>

#define BB 64
#define TT 512
#define FF 512
#define DIN 1024
#define HH 1024
#define G4 4096
#define DOUT 128

typedef _Float16 f16;
typedef _Float16 f16x8 __attribute__((ext_vector_type(8)));
typedef float f32x4 __attribute__((ext_vector_type(4)));

// A-fragment-linear layout for a [64 x 1024] fp16 activation matrix:
//   element (m, k) -> ((k>>5)*4 + (m>>4))*512 + ((((k>>3)&3)<<4) | (m&15))*8 + (k&7)
__device__ __forceinline__ size_t afrag_off(int m, int k) {
    return (size_t)(((k >> 5) * 4 + (m >> 4)) * 512 + (((((k >> 3) & 3) << 4) | (m & 15)) * 8) + (k & 7));
}

// ---------------------------------------------------------------------------
// Pack cat(W,U) [2048 x 4096] fp32 -> fp16 B-fragment-linear, z-cols reordered
// as col' = j*4 + g. Per (cg, kstep) a contiguous 1KB fragment tile.
// ---------------------------------------------------------------------------
__global__ __launch_bounds__(64) void k_pack(
    const float* __restrict__ W, const float* __restrict__ U, f16* __restrict__ out)
{
    const int kstep = blockIdx.x, cg = blockIdx.y, l = threadIdx.x;
    const int n = l & 15, q = l >> 4;
    const int stdcol = (n & 3) * HH + cg * 4 + (n >> 2);
    f16x8 v;
#pragma unroll
    for (int e = 0; e < 8; ++e) {
        int k = kstep * 32 + q * 8 + e;
        float s = (k < DIN) ? W[(size_t)k * G4 + stdcol] : U[(size_t)(k - DIN) * G4 + stdcol];
        v[e] = (f16)s;
    }
    *(f16x8*)(out + ((size_t)(cg * 64 + kstep) * 64 + l) * 8) = v;
}

// ---------------------------------------------------------------------------
// Kernel 1: XinF[t] = tanh(x[b][t][:] @ Wi + bi), written fp16 A-frag layout.
// ---------------------------------------------------------------------------
__global__ __launch_bounds__(256) void k_dense_in(
    const float* __restrict__ x, const float* __restrict__ Wi,
    const float* __restrict__ bi, f16* __restrict__ XinF)
{
    __shared__ float xs[16][FF];   // 32 KB
    const int jb  = blockIdx.x;
    const int rb  = blockIdx.y;
    const int tid = threadIdx.x;

    const float4* xsrc = (const float4*)(x + (size_t)rb * 16 * FF);
    float4* xdst = (float4*)(&xs[0][0]);
#pragma unroll
    for (int i = 0; i < 8; ++i) xdst[tid + i * 256] = xsrc[tid + i * 256];
    __syncthreads();

    const int j = jb * 256 + tid;
    float acc[16];
#pragma unroll
    for (int r = 0; r < 16; ++r) acc[r] = 0.f;

    for (int k = 0; k < FF; ++k) {
        float w = Wi[(size_t)k * DIN + j];
#pragma unroll
        for (int r = 0; r < 16; ++r) acc[r] += xs[r][k] * w;
    }
    const float bbv = bi[j];
#pragma unroll
    for (int r = 0; r < 16; ++r) {
        int g = rb * 16 + r;
        int b = g >> 9;
        int t = g & 511;
        XinF[(size_t)t * (BB * DIN) + afrag_off(b, j)] = (f16)tanhf(acc[r] + bbv);
    }
}

// ---------------------------------------------------------------------------
// Distributed flag barrier: block bid release-stores its OWN flag (no RMW
// contention); threads 0..255 poll one flag each (independent lines, agent
// scope). Acquire fence after the poll invalidates L1/L2 so h refetches
// come from IF once per XCD and are then L2-shared.
// Callers must drain vmcnt + __syncthreads BEFORE calling (so all waves'
// h-stores are in L2 when tid0's release-store wbl2 flushes them).
// ---------------------------------------------------------------------------
__device__ __forceinline__ void gbar(unsigned* flags, int bid, unsigned target) {
    if (threadIdx.x == 0)
        __hip_atomic_store(&flags[bid], target, __ATOMIC_RELEASE, __HIP_MEMORY_SCOPE_AGENT);
    if (threadIdx.x < 256) {
        while (__hip_atomic_load(&flags[threadIdx.x], __ATOMIC_RELAXED,
                                 __HIP_MEMORY_SCOPE_AGENT) < target)
            __builtin_amdgcn_s_sleep(1);
    }
    __syncthreads();
    __builtin_amdgcn_fence(__ATOMIC_ACQUIRE, "agent");
}

// ---------------------------------------------------------------------------
// Persistent kernel, 256 blocks x 512 threads (1 block/CU), flag barrier.
// Block: lay = bid&1, cgb = bid>>1 (8 hidden units = 2 N-tiles).
// Weights: block's 128 KB B-slice staged in LDS ONCE, ds_read_b128 per phase.
// Waves (8) = kq(4-way K-split) x mh(2 M-halves); each wave: 16 ksteps x
// 2 M x 2 N = 64 MFMAs. c lives in registers.
// ---------------------------------------------------------------------------
__global__ __launch_bounds__(512, 2) void k_persist(
    const f16* __restrict__ XinF,
    f16* __restrict__ h0p0, f16* __restrict__ h0p1,
    f16* __restrict__ h1p0, f16* __restrict__ h1p1,
    const f16* __restrict__ pW0, const f16* __restrict__ pW1,
    const float* __restrict__ b0, const float* __restrict__ b1,
    unsigned* __restrict__ flags)
{
    extern __shared__ char smem[];
    f16*   bsh = (f16*)smem;                    // 131072 B weight fragments
    float* red = (float*)(smem + 131072);       // 16 tiles x 260 floats = 16640 B

    const int lay = blockIdx.x & 1;
    const int cgb = blockIdx.x >> 1;
    const int tid = threadIdx.x;
    const int ws = tid >> 6, lane = tid & 63;
    const int kq = ws >> 1, mh = ws & 1;

    // ---- stage this block's weight slice into LDS (once) ----
    {
        const f16x8* s8 = (const f16x8*)((lay ? pW1 : pW0) + (size_t)(cgb * 2) * 64 * 512);
        f16x8* d8 = (f16x8*)bsh;
#pragma unroll
        for (int it = 0; it < 16; ++it) d8[tid + it * 512] = s8[tid + it * 512];
    }

    // ---- epilogue-role constants (threads 0..255: (row, jl) x 2 N-rounds) ----
    const float* bias = lay ? b1 : b0;
    const int erow = tid & 63, ejl = (tid >> 6) & 3;
    const int emt = erow >> 4, esub = erow & 15;
    const int eslq = (esub >> 2) << 4, ereg = esub & 3;
    float bz[2][4];
    float creg[2] = {0.f, 0.f};
    if (tid < 256) {
#pragma unroll
        for (int n = 0; n < 2; ++n) {
            const int jg = (cgb * 2 + n) * 4 + ejl;
#pragma unroll
            for (int g = 0; g < 4; ++g) bz[n][g] = bias[g * HH + jg];
        }
    }

    const size_t ABUF = (size_t)BB * DIN;
    __syncthreads();

    for (int p = 0; p <= TT; ++p) {
        const bool active = lay ? (p > 0) : (p < TT);
        if (active) {
            const int wp = p & 1, rp = wp ^ 1;
            const f16* h0r = rp ? h0p1 : h0p0;
            const f16* A1 = lay ? h0r : (XinF + (size_t)p * ABUF);
            const f16* A2 = lay ? (rp ? h1p1 : h1p0) : h0r;
            f16* hw = lay ? (wp ? h1p1 : h1p0) : (wp ? h0p1 : h0p0);

            const f16* Ap = ((kq < 2) ? A1 : A2)
                          + (size_t)(((kq & 1) * 64 + mh * 2) * 512) + (size_t)lane * 8;
            const f16* bq = bsh + (size_t)(kq * 16 * 64 + lane) * 8;

            f32x4 acc00 = {0.f,0.f,0.f,0.f}, acc01 = {0.f,0.f,0.f,0.f};
            f32x4 acc10 = {0.f,0.f,0.f,0.f}, acc11 = {0.f,0.f,0.f,0.f};
#pragma unroll
            for (int ii = 0; ii < 16; ++ii) {
                f16x8 a0  = *(const f16x8*)(Ap + (size_t)(ii * 4) * 512);
                f16x8 a1  = *(const f16x8*)(Ap + (size_t)(ii * 4 + 1) * 512);
                f16x8 bb0 = *(const f16x8*)(bq + (size_t)ii * 512);
                f16x8 bb1 = *(const f16x8*)(bq + 32768 + (size_t)ii * 512);
                acc00 = __builtin_amdgcn_mfma_f32_16x16x32_f16(a0, bb0, acc00, 0, 0, 0);
                acc01 = __builtin_amdgcn_mfma_f32_16x16x32_f16(a0, bb1, acc01, 0, 0, 0);
                acc10 = __builtin_amdgcn_mfma_f32_16x16x32_f16(a1, bb0, acc10, 0, 0, 0);
                acc11 = __builtin_amdgcn_mfma_f32_16x16x32_f16(a1, bb1, acc11, 0, 0, 0);
            }

            // ---- two epilogue rounds (N-tile n = 0, 1) ----
#pragma unroll
            for (int n = 0; n < 2; ++n) {
                f32x4 t0 = n ? acc01 : acc00;
                f32x4 t1 = n ? acc11 : acc10;
                *(f32x4*)(red + (size_t)(kq * 4 + mh * 2)     * 260 + lane * 4) = t0;
                *(f32x4*)(red + (size_t)(kq * 4 + mh * 2 + 1) * 260 + lane * 4) = t1;
                __syncthreads();
                if (tid < 256) {
                    float z[4];
#pragma unroll
                    for (int g = 0; g < 4; ++g) {
                        const int sl = eslq | (ejl * 4 + g);
                        float s = 0.f;
#pragma unroll
                        for (int k2 = 0; k2 < 4; ++k2)
                            s += red[(size_t)(k2 * 4 + emt) * 260 + sl * 4 + ereg];
                        z[g] = s + bz[n][g];
                    }
                    const float ig = 1.f / (1.f + expf(-z[0]));
                    const float fg = 1.f / (1.f + expf(-z[1]));
                    const float cc = tanhf(z[2]);
                    const float og = 1.f / (1.f + expf(-z[3]));
                    const float cn = fg * creg[n] + ig * cc;
                    creg[n] = cn;
                    const int jg = (cgb * 2 + n) * 4 + ejl;
                    hw[afrag_off(erow, jg)] = (f16)(og * tanhf(cn));
                }
                __syncthreads();
            }
            // drain this wave's h-stores into L2 before arrival
            asm volatile("s_waitcnt vmcnt(0)" ::: "memory");
            __syncthreads();
        }
        gbar(flags, blockIdx.x, (unsigned)(p + 1));
    }
}

// ---------------------------------------------------------------------------
// Kernel 3: out[b][o] = tanh(h1[b,:] @ Wo[:,o] + bo[o]); h1 in fp16 A-frag.
// ---------------------------------------------------------------------------
__global__ __launch_bounds__(128) void k_out(
    const f16* __restrict__ h1f, const float* __restrict__ Wo,
    const float* __restrict__ bo, float* __restrict__ out)
{
    __shared__ float hs[HH];
    const int b = blockIdx.x;
    for (int i = threadIdx.x; i < HH; i += 128) hs[i] = (float)h1f[afrag_off(b, i)];
    __syncthreads();
    const int o = threadIdx.x;
    float acc = 0.f;
    for (int k = 0; k < HH; ++k) acc += hs[k] * Wo[k * DOUT + o];
    out[b * DOUT + o] = tanhf(acc + bo[o]);
}

// ---------------------------------------------------------------------------
extern "C" void kernel_launch(void* const* d_in, const int* in_sizes, int n_in,
                              void* d_out, int out_size, void* d_ws, size_t ws_size,
                              hipStream_t stream)
{
    const float* x  = (const float*)d_in[0];
    const float* Wi = (const float*)d_in[1];
    const float* bi = (const float*)d_in[2];
    const float* W0 = (const float*)d_in[3];
    const float* U0 = (const float*)d_in[4];
    const float* b0 = (const float*)d_in[5];
    const float* W1 = (const float*)d_in[6];
    const float* U1 = (const float*)d_in[7];
    const float* b1 = (const float*)d_in[8];
    const float* Wo = (const float*)d_in[9];
    const float* bo = (const float*)d_in[10];
    float* out = (float*)d_out;

    f16* ws16 = (f16*)d_ws;
    const size_t ABUF = (size_t)BB * DIN;
    f16* XinF = ws16;
    f16* pW0  = XinF + (size_t)TT * ABUF;
    f16* pW1  = pW0 + (size_t)2048 * G4;
    f16* h0a  = pW1 + (size_t)2048 * G4;
    f16* h0b  = h0a + ABUF;
    f16* h1a  = h0b + ABUF;
    f16* h1b  = h1a + ABUF;
    unsigned* flags = (unsigned*)(h1b + ABUF);   // 256 words

    // zero h (both parities) + flag array — contiguous region
    hipMemsetAsync(h0a, 0, 4 * ABUF * sizeof(f16) + 256 * sizeof(unsigned), stream);

    k_pack<<<dim3(64, 256), 64, 0, stream>>>(W0, U0, pW0);
    k_pack<<<dim3(64, 256), 64, 0, stream>>>(W1, U1, pW1);
    k_dense_in<<<dim3(DIN / 256, (BB * TT) / 16), 256, 0, stream>>>(x, Wi, bi, XinF);

    {
        const int smem_bytes = 131072 + 16640;   // 147712 B
        hipFuncSetAttribute((const void*)k_persist,
                            hipFuncAttributeMaxDynamicSharedMemorySize, smem_bytes);
        const f16* XinF_c = XinF;
        const f16* pW0_c = pW0;
        const f16* pW1_c = pW1;
        f16 *h0a_v = h0a, *h0b_v = h0b, *h1a_v = h1a, *h1b_v = h1b;
        const float *b0_v = b0, *b1_v = b1;
        unsigned* flags_v = flags;
        void* kargs[] = {
            (void*)&XinF_c,
            (void*)&h0a_v, (void*)&h0b_v, (void*)&h1a_v, (void*)&h1b_v,
            (void*)&pW0_c, (void*)&pW1_c,
            (void*)&b0_v, (void*)&b1_v,
            (void*)&flags_v
        };
        hipLaunchCooperativeKernel((void*)k_persist, dim3(256), dim3(512),
                                   kargs, smem_bytes, stream);
    }

    // phase TT writes parity 0 -> h1a holds h1[T-1]
    k_out<<<BB, 128, 0, stream>>>(h1a, Wo, bo, out);
}

// Round 7
// 4994.990 us; speedup vs baseline: 4.4399x; 2.9355x over previous
//
#include <hip/hip_runtime.h>
#include <math.h>

#define BB 64
#define TT 512
#define FF 512
#define DIN 1024
#define HH 1024
#define G4 4096
#define DOUT 128

typedef _Float16 f16;
typedef _Float16 f16x8 __attribute__((ext_vector_type(8)));
typedef float f32x4 __attribute__((ext_vector_type(4)));

// A-fragment-linear layout for a [64 x 1024] fp16 activation matrix:
//   element (m, k) -> ((k>>5)*4 + (m>>4))*512 + ((((k>>3)&3)<<4) | (m&15))*8 + (k&7)
__device__ __forceinline__ size_t afrag_off(int m, int k) {
    return (size_t)(((k >> 5) * 4 + (m >> 4)) * 512 + (((((k >> 3) & 3) << 4) | (m & 15)) * 8) + (k & 7));
}

// agent-scope write-through store of one f16 (bypasses/写-through past XCD L2
// so the IF copy is authoritative for cross-XCD readers)
__device__ __forceinline__ void store_f16_sc1(f16* p, f16 v) {
    short s = __builtin_bit_cast(short, v);
    asm volatile("global_store_short %0, %1, off sc1" :: "v"(p), "v"(s) : "memory");
}

// ---------------------------------------------------------------------------
// Pack cat(W,U) [2048 x 4096] fp32 -> fp16 B-fragment-linear, z-cols reordered
// as col' = j*4 + g. Per (cg, kstep) a contiguous 1KB fragment tile.
// ---------------------------------------------------------------------------
__global__ __launch_bounds__(64) void k_pack(
    const float* __restrict__ W, const float* __restrict__ U, f16* __restrict__ out)
{
    const int kstep = blockIdx.x, cg = blockIdx.y, l = threadIdx.x;
    const int n = l & 15, q = l >> 4;
    const int stdcol = (n & 3) * HH + cg * 4 + (n >> 2);
    f16x8 v;
#pragma unroll
    for (int e = 0; e < 8; ++e) {
        int k = kstep * 32 + q * 8 + e;
        float s = (k < DIN) ? W[(size_t)k * G4 + stdcol] : U[(size_t)(k - DIN) * G4 + stdcol];
        v[e] = (f16)s;
    }
    *(f16x8*)(out + ((size_t)(cg * 64 + kstep) * 64 + l) * 8) = v;
}

// ---------------------------------------------------------------------------
// Kernel 1: XinF[t] = tanh(x[b][t][:] @ Wi + bi), written fp16 A-frag layout.
// ---------------------------------------------------------------------------
__global__ __launch_bounds__(256) void k_dense_in(
    const float* __restrict__ x, const float* __restrict__ Wi,
    const float* __restrict__ bi, f16* __restrict__ XinF)
{
    __shared__ float xs[16][FF];   // 32 KB
    const int jb  = blockIdx.x;
    const int rb  = blockIdx.y;
    const int tid = threadIdx.x;

    const float4* xsrc = (const float4*)(x + (size_t)rb * 16 * FF);
    float4* xdst = (float4*)(&xs[0][0]);
#pragma unroll
    for (int i = 0; i < 8; ++i) xdst[tid + i * 256] = xsrc[tid + i * 256];
    __syncthreads();

    const int j = jb * 256 + tid;
    float acc[16];
#pragma unroll
    for (int r = 0; r < 16; ++r) acc[r] = 0.f;

    for (int k = 0; k < FF; ++k) {
        float w = Wi[(size_t)k * DIN + j];
#pragma unroll
        for (int r = 0; r < 16; ++r) acc[r] += xs[r][k] * w;
    }
    const float bbv = bi[j];
#pragma unroll
    for (int r = 0; r < 16; ++r) {
        int g = rb * 16 + r;
        int b = g >> 9;
        int t = g & 511;
        XinF[(size_t)t * (BB * DIN) + afrag_off(b, j)] = (f16)tanhf(acc[r] + bbv);
    }
}

// ---------------------------------------------------------------------------
// Persistent kernel, 256 blocks x 512 threads (1 block/CU).
// Block: lay = bid&1, cgb = bid>>1 (8 hidden units = 2 N-tiles).
// Weights: block's 128 KB B-slice staged in LDS ONCE.
// h state: WRITE-ONCE history buffers (513 per layer) — no stale-line hazard,
// so reads are normal cached loads; writes are sc1 write-through (IF
// authoritative). NO cache-maintenance fences anywhere.
// Barrier: each block release-stores its own flag; block 0 wave 0 aggregates
// all 256 flags and publishes one `go` word; all tid0s poll go only.
// ---------------------------------------------------------------------------
__global__ __launch_bounds__(512, 2) void k_persist(
    const f16* __restrict__ XinF,
    f16* __restrict__ h0b_, f16* __restrict__ h1b_,
    const f16* __restrict__ pW0, const f16* __restrict__ pW1,
    const float* __restrict__ b0, const float* __restrict__ b1,
    unsigned* __restrict__ flags)
{
    extern __shared__ char smem[];
    f16*   bsh = (f16*)smem;                    // 131072 B weight fragments
    float* red = (float*)(smem + 131072);       // 16 tiles x 260 floats

    const int lay = blockIdx.x & 1;
    const int cgb = blockIdx.x >> 1;
    const int tid = threadIdx.x;
    const int wv = tid >> 6, lane = tid & 63;
    const int kq = wv >> 1, mh = wv & 1;
    unsigned* go = flags + 1024;                // own cacheline (4KB offset)

    // ---- stage this block's weight slice into LDS (once) ----
    {
        const f16x8* s8 = (const f16x8*)((lay ? pW1 : pW0) + (size_t)(cgb * 2) * 64 * 512);
        f16x8* d8 = (f16x8*)bsh;
#pragma unroll
        for (int it = 0; it < 16; ++it) d8[tid + it * 512] = s8[tid + it * 512];
    }

    // ---- epilogue-role constants ----
    const float* bias = lay ? b1 : b0;
    const int erow = tid & 63, ejl = (tid >> 6) & 3;
    const int emt = erow >> 4, esub = erow & 15;
    const int eslq = (esub >> 2) << 4, ereg = esub & 3;
    float bz[2][4];
    float creg[2] = {0.f, 0.f};
    if (tid < 256) {
#pragma unroll
        for (int n = 0; n < 2; ++n) {
            const int jg = (cgb * 2 + n) * 4 + ejl;
#pragma unroll
            for (int g = 0; g < 4; ++g) bz[n][g] = bias[g * HH + jg];
        }
    }

    const size_t HBUF = (size_t)BB * DIN;
    __syncthreads();

    for (int p = 0; p <= TT; ++p) {
        const bool active = lay ? (p > 0) : (p < TT);
        if (active) {
            // write-once history indexing: h0[t] lives at h0b_+(t+1)*HBUF
            const f16* h0r = h0b_ + (size_t)p * HBUF;                 // h0[p-1]
            const f16* A1 = lay ? h0r : (XinF + (size_t)p * HBUF);
            const f16* A2 = lay ? (h1b_ + (size_t)(p - 1) * HBUF)     // h1[p-2]
                                : h0r;
            f16* hw = lay ? (h1b_ + (size_t)p * HBUF)                 // h1[p-1]
                          : (h0b_ + (size_t)(p + 1) * HBUF);          // h0[p]

            const f16* Ap = ((kq < 2) ? A1 : A2)
                          + (size_t)(((kq & 1) * 64 + mh * 2) * 512) + (size_t)lane * 8;
            const f16* bq = bsh + (size_t)(kq * 16 * 64 + lane) * 8;

            f32x4 acc00 = {0.f,0.f,0.f,0.f}, acc01 = {0.f,0.f,0.f,0.f};
            f32x4 acc10 = {0.f,0.f,0.f,0.f}, acc11 = {0.f,0.f,0.f,0.f};
#pragma unroll
            for (int ii = 0; ii < 16; ++ii) {
                f16x8 a0  = *(const f16x8*)(Ap + (size_t)(ii * 4) * 512);
                f16x8 a1  = *(const f16x8*)(Ap + (size_t)(ii * 4 + 1) * 512);
                f16x8 bb0 = *(const f16x8*)(bq + (size_t)ii * 512);
                f16x8 bb1 = *(const f16x8*)(bq + 32768 + (size_t)ii * 512);
                acc00 = __builtin_amdgcn_mfma_f32_16x16x32_f16(a0, bb0, acc00, 0, 0, 0);
                acc01 = __builtin_amdgcn_mfma_f32_16x16x32_f16(a0, bb1, acc01, 0, 0, 0);
                acc10 = __builtin_amdgcn_mfma_f32_16x16x32_f16(a1, bb0, acc10, 0, 0, 0);
                acc11 = __builtin_amdgcn_mfma_f32_16x16x32_f16(a1, bb1, acc11, 0, 0, 0);
            }

            // ---- two epilogue rounds (N-tile n = 0, 1) ----
#pragma unroll
            for (int n = 0; n < 2; ++n) {
                f32x4 t0 = n ? acc01 : acc00;
                f32x4 t1 = n ? acc11 : acc10;
                *(f32x4*)(red + (size_t)(kq * 4 + mh * 2)     * 260 + lane * 4) = t0;
                *(f32x4*)(red + (size_t)(kq * 4 + mh * 2 + 1) * 260 + lane * 4) = t1;
                __syncthreads();
                if (tid < 256) {
                    float z[4];
#pragma unroll
                    for (int g = 0; g < 4; ++g) {
                        const int sl = eslq | (ejl * 4 + g);
                        float s = 0.f;
#pragma unroll
                        for (int k2 = 0; k2 < 4; ++k2)
                            s += red[(size_t)(k2 * 4 + emt) * 260 + sl * 4 + ereg];
                        z[g] = s + bz[n][g];
                    }
                    const float ig = 1.f / (1.f + expf(-z[0]));
                    const float fg = 1.f / (1.f + expf(-z[1]));
                    const float cc = tanhf(z[2]);
                    const float og = 1.f / (1.f + expf(-z[3]));
                    const float cn = fg * creg[n] + ig * cc;
                    creg[n] = cn;
                    const int jg = (cgb * 2 + n) * 4 + ejl;
                    store_f16_sc1(&hw[afrag_off(erow, jg)], (f16)(og * tanhf(cn)));
                }
                __syncthreads();
            }
        }

        // ---- barrier: data (sc1 stores) ordered before flag by vmcnt drain ----
        asm volatile("s_waitcnt vmcnt(0)" ::: "memory");
        __syncthreads();
        const unsigned tgt = (unsigned)(p + 1);
        if (tid == 0)
            __hip_atomic_store(&flags[blockIdx.x], tgt, __ATOMIC_RELAXED,
                               __HIP_MEMORY_SCOPE_AGENT);
        if (blockIdx.x == 0 && tid < 64) {
            for (;;) {
                bool ok = true;
#pragma unroll
                for (int q = 0; q < 4; ++q)
                    ok = ok && (__hip_atomic_load(&flags[lane + q * 64], __ATOMIC_RELAXED,
                                                  __HIP_MEMORY_SCOPE_AGENT) >= tgt);
                if (__all(ok)) break;
                __builtin_amdgcn_s_sleep(1);
            }
            if (tid == 0)
                __hip_atomic_store(go, tgt, __ATOMIC_RELAXED, __HIP_MEMORY_SCOPE_AGENT);
        }
        if (tid == 0) {
            while (__hip_atomic_load(go, __ATOMIC_RELAXED, __HIP_MEMORY_SCOPE_AGENT) < tgt)
                __builtin_amdgcn_s_sleep(1);
        }
        __syncthreads();
    }
}

// ---------------------------------------------------------------------------
// Kernel 3: out[b][o] = tanh(h1[b,:] @ Wo[:,o] + bo[o]); h1 in fp16 A-frag.
// ---------------------------------------------------------------------------
__global__ __launch_bounds__(128) void k_out(
    const f16* __restrict__ h1f, const float* __restrict__ Wo,
    const float* __restrict__ bo, float* __restrict__ out)
{
    __shared__ float hs[HH];
    const int b = blockIdx.x;
    for (int i = threadIdx.x; i < HH; i += 128) hs[i] = (float)h1f[afrag_off(b, i)];
    __syncthreads();
    const int o = threadIdx.x;
    float acc = 0.f;
    for (int k = 0; k < HH; ++k) acc += hs[k] * Wo[k * DOUT + o];
    out[b * DOUT + o] = tanhf(acc + bo[o]);
}

// ---------------------------------------------------------------------------
extern "C" void kernel_launch(void* const* d_in, const int* in_sizes, int n_in,
                              void* d_out, int out_size, void* d_ws, size_t ws_size,
                              hipStream_t stream)
{
    const float* x  = (const float*)d_in[0];
    const float* Wi = (const float*)d_in[1];
    const float* bi = (const float*)d_in[2];
    const float* W0 = (const float*)d_in[3];
    const float* U0 = (const float*)d_in[4];
    const float* b0 = (const float*)d_in[5];
    const float* W1 = (const float*)d_in[6];
    const float* U1 = (const float*)d_in[7];
    const float* b1 = (const float*)d_in[8];
    const float* Wo = (const float*)d_in[9];
    const float* bo = (const float*)d_in[10];
    float* out = (float*)d_out;

    f16* ws16 = (f16*)d_ws;
    const size_t HBUF = (size_t)BB * DIN;          // 65536 f16
    f16* XinF = ws16;                              // 512 bufs
    f16* pW0  = XinF + (size_t)TT * HBUF;
    f16* pW1  = pW0 + (size_t)2048 * G4;
    f16* h0   = pW1 + (size_t)2048 * G4;           // 513 bufs (write-once hist)
    f16* h1   = h0 + (size_t)513 * HBUF;           // 513 bufs
    unsigned* flags = (unsigned*)(h1 + (size_t)513 * HBUF);  // 256 + go @ +1024

    // zero initial h0[-1], h1[-1] and the flag/go region
    hipMemsetAsync(h0, 0, HBUF * sizeof(f16), stream);
    hipMemsetAsync(h1, 0, HBUF * sizeof(f16), stream);
    hipMemsetAsync(flags, 0, 8192, stream);

    k_pack<<<dim3(64, 256), 64, 0, stream>>>(W0, U0, pW0);
    k_pack<<<dim3(64, 256), 64, 0, stream>>>(W1, U1, pW1);
    k_dense_in<<<dim3(DIN / 256, (BB * TT) / 16), 256, 0, stream>>>(x, Wi, bi, XinF);

    {
        const int smem_bytes = 131072 + 16640;   // 147712 B
        hipFuncSetAttribute((const void*)k_persist,
                            hipFuncAttributeMaxDynamicSharedMemorySize, smem_bytes);
        const f16* XinF_c = XinF;
        const f16* pW0_c = pW0;
        const f16* pW1_c = pW1;
        f16 *h0_v = h0, *h1_v = h1;
        const float *b0_v = b0, *b1_v = b1;
        unsigned* flags_v = flags;
        void* kargs[] = {
            (void*)&XinF_c,
            (void*)&h0_v, (void*)&h1_v,
            (void*)&pW0_c, (void*)&pW1_c,
            (void*)&b0_v, (void*)&b1_v,
            (void*)&flags_v
        };
        hipLaunchCooperativeKernel((void*)k_persist, dim3(256), dim3(512),
                                   kargs, smem_bytes, stream);
    }

    // h1[511] lives at h1 + 512*HBUF
    k_out<<<BB, 128, 0, stream>>>(h1 + (size_t)512 * HBUF, Wo, bo, out);
}

// Round 8
// 3392.088 us; speedup vs baseline: 6.5379x; 1.4725x over previous
//
#include <hip/hip_runtime.h>
#include <math.h>

#define BB 64
#define TT 512
#define FF 512
#define DIN 1024
#define HH 1024
#define G4 4096
#define DOUT 128

typedef _Float16 f16;
typedef _Float16 f16x4 __attribute__((ext_vector_type(4)));
typedef _Float16 f16x8 __attribute__((ext_vector_type(8)));
typedef float f32x4 __attribute__((ext_vector_type(4)));

// A-fragment-linear layout for a [64 x 1024] fp16 activation matrix:
//   element (m, k) -> ((k>>5)*4 + (m>>4))*512 + ((((k>>3)&3)<<4) | (m&15))*8 + (k&7)
__device__ __forceinline__ size_t afrag_off(int m, int k) {
    return (size_t)(((k >> 5) * 4 + (m >> 4)) * 512 + (((((k >> 3) & 3) << 4) | (m & 15)) * 8) + (k & 7));
}

// agent-scope write-through 16-B store (IF authoritative for cross-XCD readers)
__device__ __forceinline__ void store_b128_sc1(void* p, f32x4 v) {
    asm volatile("global_store_dwordx4 %0, %1, off sc1" :: "v"(p), "v"(v) : "memory");
}

// ---------------------------------------------------------------------------
// Pack cat(W,U) [2048 x 4096] fp32 -> fp16 B-fragment-linear, z-cols reordered
// as col' = j*4 + g. Per (cg, kstep) a contiguous 1KB fragment tile.
// ---------------------------------------------------------------------------
__global__ __launch_bounds__(64) void k_pack(
    const float* __restrict__ W, const float* __restrict__ U, f16* __restrict__ out)
{
    const int kstep = blockIdx.x, cg = blockIdx.y, l = threadIdx.x;
    const int n = l & 15, q = l >> 4;
    const int stdcol = (n & 3) * HH + cg * 4 + (n >> 2);
    f16x8 v;
#pragma unroll
    for (int e = 0; e < 8; ++e) {
        int k = kstep * 32 + q * 8 + e;
        float s = (k < DIN) ? W[(size_t)k * G4 + stdcol] : U[(size_t)(k - DIN) * G4 + stdcol];
        v[e] = (f16)s;
    }
    *(f16x8*)(out + ((size_t)(cg * 64 + kstep) * 64 + l) * 8) = v;
}

// ---------------------------------------------------------------------------
// Pack Wi [512 x 1024] fp32 -> fp16 B-frag (no gate reorder). Tile (nt, kstep).
// ---------------------------------------------------------------------------
__global__ __launch_bounds__(64) void k_pack_wi(
    const float* __restrict__ Wi, f16* __restrict__ out)
{
    const int kstep = blockIdx.x;   // 0..15
    const int nt    = blockIdx.y;   // 0..63
    const int l = threadIdx.x;
    const int n = nt * 16 + (l & 15), q = l >> 4;
    f16x8 v;
#pragma unroll
    for (int e = 0; e < 8; ++e)
        v[e] = (f16)Wi[(size_t)(kstep * 32 + q * 8 + e) * DIN + n];
    *(f16x8*)(out + ((size_t)(nt * 16 + kstep) * 64 + l) * 8) = v;
}

// ---------------------------------------------------------------------------
// MFMA input dense: XinF[t] = tanh(x[:,t,:] @ Wi + bi), f16 A-frag layout.
// One block per t; stage x[:,t,:] as f16 in LDS [64][520]; 4 waves x 4 N-groups.
// ---------------------------------------------------------------------------
__global__ __launch_bounds__(256) void k_dense_in2(
    const float* __restrict__ x, const f16* __restrict__ pWi,
    const float* __restrict__ bi, f16* __restrict__ XinF)
{
    extern __shared__ f16 xs[];   // 64 x 520 = 66560 B
    const int t = blockIdx.x;
    const int tid = threadIdx.x;

#pragma unroll
    for (int it = 0; it < 32; ++it) {
        int idx = tid + it * 256;          // 0..8191 float4s
        int r = idx >> 7, c4 = idx & 127;
        float4 v = *(const float4*)(x + ((size_t)r * TT + t) * FF + c4 * 4);
        f16x4 hv = {(f16)v.x, (f16)v.y, (f16)v.z, (f16)v.w};
        *(f16x4*)(xs + (size_t)r * 520 + c4 * 4) = hv;
    }
    __syncthreads();

    const int w = tid >> 6, lane = tid & 63;
    const int col = lane & 15, rq = lane >> 4;
#pragma unroll 1
    for (int g = 0; g < 4; ++g) {
        f32x4 acc[4][4];
#pragma unroll
        for (int a = 0; a < 4; ++a)
#pragma unroll
            for (int b = 0; b < 4; ++b) acc[a][b] = (f32x4){0.f, 0.f, 0.f, 0.f};
#pragma unroll 2
        for (int ks2 = 0; ks2 < 16; ++ks2) {
            f16x8 bf[4];
#pragma unroll
            for (int nn = 0; nn < 4; ++nn)
                bf[nn] = *(const f16x8*)(pWi + ((size_t)((w * 16 + g * 4 + nn) * 16 + ks2) * 64 + lane) * 8);
#pragma unroll
            for (int mt = 0; mt < 4; ++mt) {
                f16x8 af = *(const f16x8*)(xs + (size_t)(mt * 16 + col) * 520 + ks2 * 32 + rq * 8);
#pragma unroll
                for (int nn = 0; nn < 4; ++nn)
                    acc[mt][nn] = __builtin_amdgcn_mfma_f32_16x16x32_f16(af, bf[nn], acc[mt][nn], 0, 0, 0);
            }
        }
#pragma unroll
        for (int nn = 0; nn < 4; ++nn) {
            const int j = (w * 16 + g * 4 + nn) * 16 + col;
            const float bb = bi[j];
#pragma unroll
            for (int mt = 0; mt < 4; ++mt)
#pragma unroll
                for (int r = 0; r < 4; ++r)
                    XinF[(size_t)t * (BB * DIN) + afrag_off(mt * 16 + rq * 4 + r, j)]
                        = (f16)tanhf(acc[mt][nn][r] + bb);
        }
    }
}

// ---------------------------------------------------------------------------
// Persistent kernel, 256 blocks x 512 threads (1 block/CU).
// lay = bid&1, cgb = bid>>1 (8 hidden units). Weights in LDS once.
// Decoupled per-layer barriers: arrivals on flags0/flags1 (own word), master
// blocks (bid 0 for L0, bid 1 for L1) aggregate and publish go0/go1.
// L0 waits only go0; L1 waits go0 (usually pre-satisfied) + go1.
// h: write-once history, sc1 write-through 16-B stores; Xin prefetched
// pre-barrier by L0's kq<2 waves. Cell state c in registers.
// ---------------------------------------------------------------------------
__global__ __launch_bounds__(512, 2) void k_persist(
    const f16* __restrict__ XinF,
    f16* __restrict__ h0b_, f16* __restrict__ h1b_,
    const f16* __restrict__ pW0, const f16* __restrict__ pW1,
    const float* __restrict__ b0, const float* __restrict__ b1,
    unsigned* __restrict__ flags)
{
    extern __shared__ char smem[];
    f16*   bsh = (f16*)smem;                    // 131072 B weight fragments
    float* red = (float*)(smem + 131072);       // 16 tiles x 260 floats

    const int lay = blockIdx.x & 1;
    const int cgb = blockIdx.x >> 1;
    const int tid = threadIdx.x;
    const int wv = tid >> 6, lane = tid & 63;
    const int kq = wv >> 1, mh = wv & 1;

    unsigned* fl   = flags + (lay ? 1024 : 0);   // own-layer arrival words
    unsigned* goO  = flags + 2048 + (lay ? 32 : 0);
    unsigned* go0p = flags + 2048;
    const bool isAgg = (cgb == 0);

    // ---- stage this block's weight slice into LDS (once) ----
    {
        const f16x8* s8 = (const f16x8*)((lay ? pW1 : pW0) + (size_t)(cgb * 2) * 64 * 512);
        f16x8* d8 = (f16x8*)bsh;
#pragma unroll
        for (int it = 0; it < 16; ++it) d8[tid + it * 512] = s8[tid + it * 512];
    }

    // ---- epilogue-role constants ----
    const float* bias = lay ? b1 : b0;
    const int erow = tid & 63, ejl = (tid >> 6) & 3;
    const int emt = erow >> 4, esub = erow & 15;
    const int eslq = (esub >> 2) << 4, ereg = esub & 3;
    float bz[2][4];
    float creg[2] = {0.f, 0.f};
    if (tid < 256) {
#pragma unroll
        for (int n = 0; n < 2; ++n) {
            const int jg = (cgb * 2 + n) * 4 + ejl;
#pragma unroll
            for (int g = 0; g < 4; ++g) bz[n][g] = bias[g * HH + jg];
        }
    }

    const size_t HBUF = (size_t)BB * DIN;
    const f16* bq = bsh + (size_t)(kq * 16 * 64 + lane) * 8;
    __syncthreads();

    for (int p = 0; p <= TT; ++p) {
        if (lay == 0 && p == TT) break;          // L0 finished at p=511
        const bool active = lay ? (p >= 1) : true;

        if (active) {
            const f16* Abase;
            if (lay == 0) Abase = (kq < 2) ? (XinF + (size_t)p * HBUF) : (h0b_ + (size_t)p * HBUF);
            else          Abase = (kq < 2) ? (h0b_ + (size_t)p * HBUF) : (h1b_ + (size_t)(p - 1) * HBUF);
            f16* hw = lay ? (h1b_ + (size_t)p * HBUF) : (h0b_ + (size_t)(p + 1) * HBUF);
            const f16* Ap = Abase + (size_t)(((kq & 1) * 64 + mh * 2) * 512) + (size_t)lane * 8;

            f16x8 a0v[16], a1v[16];
            const bool pre = (lay == 0) && (kq < 2);   // Xin is static: safe pre-barrier
            if (pre) {
#pragma unroll
                for (int ii = 0; ii < 16; ++ii) {
                    a0v[ii] = *(const f16x8*)(Ap + (size_t)(ii * 4) * 512);
                    a1v[ii] = *(const f16x8*)(Ap + (size_t)(ii * 4 + 1) * 512);
                }
            }

            // ---- wait for phase inputs ----
            if (lay == 0) {
                if (p > 0) {
                    if (tid == 0)
                        while (__hip_atomic_load(go0p, __ATOMIC_RELAXED, __HIP_MEMORY_SCOPE_AGENT) < (unsigned)p)
                            __builtin_amdgcn_s_sleep(1);
                    __syncthreads();
                }
            } else {
                if (tid == 0) {
                    while (__hip_atomic_load(go0p, __ATOMIC_RELAXED, __HIP_MEMORY_SCOPE_AGENT) < (unsigned)p)
                        __builtin_amdgcn_s_sleep(1);
                    while (__hip_atomic_load(goO, __ATOMIC_RELAXED, __HIP_MEMORY_SCOPE_AGENT) < (unsigned)p)
                        __builtin_amdgcn_s_sleep(1);
                }
                __syncthreads();
            }

            if (!pre) {
#pragma unroll
                for (int ii = 0; ii < 16; ++ii) {
                    a0v[ii] = *(const f16x8*)(Ap + (size_t)(ii * 4) * 512);
                    a1v[ii] = *(const f16x8*)(Ap + (size_t)(ii * 4 + 1) * 512);
                }
            }

            f32x4 acc00 = {0.f,0.f,0.f,0.f}, acc01 = {0.f,0.f,0.f,0.f};
            f32x4 acc10 = {0.f,0.f,0.f,0.f}, acc11 = {0.f,0.f,0.f,0.f};
#pragma unroll
            for (int ii = 0; ii < 16; ++ii) {
                f16x8 bb0 = *(const f16x8*)(bq + (size_t)ii * 512);
                f16x8 bb1 = *(const f16x8*)(bq + 32768 + (size_t)ii * 512);
                acc00 = __builtin_amdgcn_mfma_f32_16x16x32_f16(a0v[ii], bb0, acc00, 0, 0, 0);
                acc01 = __builtin_amdgcn_mfma_f32_16x16x32_f16(a0v[ii], bb1, acc01, 0, 0, 0);
                acc10 = __builtin_amdgcn_mfma_f32_16x16x32_f16(a1v[ii], bb0, acc10, 0, 0, 0);
                acc11 = __builtin_amdgcn_mfma_f32_16x16x32_f16(a1v[ii], bb1, acc11, 0, 0, 0);
            }

            // ---- two epilogue rounds (N-tile n = 0, 1) ----
            f16 hvv[2];
#pragma unroll
            for (int n = 0; n < 2; ++n) {
                f32x4 t0 = n ? acc01 : acc00;
                f32x4 t1 = n ? acc11 : acc10;
                *(f32x4*)(red + (size_t)(kq * 4 + mh * 2)     * 260 + lane * 4) = t0;
                *(f32x4*)(red + (size_t)(kq * 4 + mh * 2 + 1) * 260 + lane * 4) = t1;
                __syncthreads();
                if (tid < 256) {
                    float z[4];
#pragma unroll
                    for (int g = 0; g < 4; ++g) {
                        const int sl = eslq | (ejl * 4 + g);
                        float s = 0.f;
#pragma unroll
                        for (int k2 = 0; k2 < 4; ++k2)
                            s += red[(size_t)(k2 * 4 + emt) * 260 + sl * 4 + ereg];
                        z[g] = s + bz[n][g];
                    }
                    const float ig = 1.f / (1.f + expf(-z[0]));
                    const float fg = 1.f / (1.f + expf(-z[1]));
                    const float cc = tanhf(z[2]);
                    const float og = 1.f / (1.f + expf(-z[3]));
                    const float cn = fg * creg[n] + ig * cc;
                    creg[n] = cn;
                    hvv[n] = (f16)(og * tanhf(cn));
                }
                __syncthreads();
            }

            // ---- repack h row-runs in LDS, one 16-B sc1 store per row ----
            f16* hrow = (f16*)red;
            if (tid < 256) {
                hrow[erow * 8 + ejl]     = hvv[0];
                hrow[erow * 8 + 4 + ejl] = hvv[1];
            }
            __syncthreads();
            if (tid < 64) {
                f32x4 v = *(f32x4*)(hrow + tid * 8);
                store_b128_sc1(hw + afrag_off(tid, cgb * 8), v);
            }
        }

        // ---- arrival + per-layer aggregation ----
        asm volatile("s_waitcnt vmcnt(0)" ::: "memory");
        __syncthreads();
        const unsigned tgt = (unsigned)(p + 1);
        if (tid == 0)
            __hip_atomic_store(&fl[cgb], tgt, __ATOMIC_RELAXED, __HIP_MEMORY_SCOPE_AGENT);
        if (isAgg) {
            if (tid < 64) {
                for (;;) {
                    bool ok = (__hip_atomic_load(&fl[lane], __ATOMIC_RELAXED, __HIP_MEMORY_SCOPE_AGENT) >= tgt)
                           && (__hip_atomic_load(&fl[lane + 64], __ATOMIC_RELAXED, __HIP_MEMORY_SCOPE_AGENT) >= tgt);
                    if (__all(ok)) break;
                    __builtin_amdgcn_s_sleep(1);
                }
                if (tid == 0)
                    __hip_atomic_store(goO, tgt, __ATOMIC_RELAXED, __HIP_MEMORY_SCOPE_AGENT);
            }
        }
    }
}

// ---------------------------------------------------------------------------
// Kernel 3: out[b][o] = tanh(h1[b,:] @ Wo[:,o] + bo[o]); h1 in fp16 A-frag.
// ---------------------------------------------------------------------------
__global__ __launch_bounds__(128) void k_out(
    const f16* __restrict__ h1f, const float* __restrict__ Wo,
    const float* __restrict__ bo, float* __restrict__ out)
{
    __shared__ float hs[HH];
    const int b = blockIdx.x;
    for (int i = threadIdx.x; i < HH; i += 128) hs[i] = (float)h1f[afrag_off(b, i)];
    __syncthreads();
    const int o = threadIdx.x;
    float acc = 0.f;
    for (int k = 0; k < HH; ++k) acc += hs[k] * Wo[k * DOUT + o];
    out[b * DOUT + o] = tanhf(acc + bo[o]);
}

// ---------------------------------------------------------------------------
extern "C" void kernel_launch(void* const* d_in, const int* in_sizes, int n_in,
                              void* d_out, int out_size, void* d_ws, size_t ws_size,
                              hipStream_t stream)
{
    const float* x  = (const float*)d_in[0];
    const float* Wi = (const float*)d_in[1];
    const float* bi = (const float*)d_in[2];
    const float* W0 = (const float*)d_in[3];
    const float* U0 = (const float*)d_in[4];
    const float* b0 = (const float*)d_in[5];
    const float* W1 = (const float*)d_in[6];
    const float* U1 = (const float*)d_in[7];
    const float* b1 = (const float*)d_in[8];
    const float* Wo = (const float*)d_in[9];
    const float* bo = (const float*)d_in[10];
    float* out = (float*)d_out;

    f16* ws16 = (f16*)d_ws;
    const size_t HBUF = (size_t)BB * DIN;          // 65536 f16
    f16* XinF = ws16;                              // 512 bufs
    f16* pW0  = XinF + (size_t)TT * HBUF;
    f16* pW1  = pW0 + (size_t)2048 * G4;
    f16* pWi  = pW1 + (size_t)2048 * G4;           // 512*1024
    f16* h0   = pWi + (size_t)FF * DIN;            // 513 bufs (write-once hist)
    f16* h1   = h0 + (size_t)513 * HBUF;           // 513 bufs
    unsigned* flags = (unsigned*)(h1 + (size_t)513 * HBUF);

    // zero initial h0[-1], h1[-1] and the flag/go region
    hipMemsetAsync(h0, 0, HBUF * sizeof(f16), stream);
    hipMemsetAsync(h1, 0, HBUF * sizeof(f16), stream);
    hipMemsetAsync(flags, 0, 16384, stream);

    k_pack<<<dim3(64, 256), 64, 0, stream>>>(W0, U0, pW0);
    k_pack<<<dim3(64, 256), 64, 0, stream>>>(W1, U1, pW1);
    k_pack_wi<<<dim3(16, 64), 64, 0, stream>>>(Wi, pWi);

    hipFuncSetAttribute((const void*)k_dense_in2,
                        hipFuncAttributeMaxDynamicSharedMemorySize, 66560);
    k_dense_in2<<<TT, 256, 66560, stream>>>(x, pWi, bi, XinF);

    {
        const int smem_bytes = 131072 + 16640;   // 147712 B
        hipFuncSetAttribute((const void*)k_persist,
                            hipFuncAttributeMaxDynamicSharedMemorySize, smem_bytes);
        const f16* XinF_c = XinF;
        const f16* pW0_c = pW0;
        const f16* pW1_c = pW1;
        f16 *h0_v = h0, *h1_v = h1;
        const float *b0_v = b0, *b1_v = b1;
        unsigned* flags_v = flags;
        void* kargs[] = {
            (void*)&XinF_c,
            (void*)&h0_v, (void*)&h1_v,
            (void*)&pW0_c, (void*)&pW1_c,
            (void*)&b0_v, (void*)&b1_v,
            (void*)&flags_v
        };
        hipLaunchCooperativeKernel((void*)k_persist, dim3(256), dim3(512),
                                   kargs, smem_bytes, stream);
    }

    // h1[511] lives at h1 + 512*HBUF
    k_out<<<BB, 128, 0, stream>>>(h1 + (size_t)512 * HBUF, Wo, bo, out);
}